// Round 2
// baseline (186.348 us; speedup 1.0000x reference)
//
#include <hip/hip_runtime.h>
#include <hip/hip_bf16.h>

#define B_N  4096
#define K_D  1024
#define TILE 128
#define BK   64
#define NBLK ((B_N / TILE) * (B_N / TILE))

typedef __bf16 bf16x8 __attribute__((ext_vector_type(8)));
typedef float  f32x4  __attribute__((ext_vector_type(4)));

// round-to-nearest-even float -> bf16 bits
__device__ __forceinline__ unsigned short f2bf(float x) {
    union { float f; unsigned int u; } v; v.f = x;
    unsigned int r = v.u + 0x7fffu + ((v.u >> 16) & 1u);
    return (unsigned short)(r >> 16);
}

// One block per row: L2 norm -> bf16 normalized row. Also zeroes the
// reduction scratch (rowsum/possum/counter) so no separate memset dispatch.
__global__ void normalize_bf16(const float* __restrict__ f, unsigned short* __restrict__ fnb,
                               float* __restrict__ rowsum, float* __restrict__ possum,
                               int* __restrict__ counter) {
    const int row = blockIdx.x;
    const int tid = threadIdx.x;
    float4 v = ((const float4*)(f + (size_t)row * K_D))[tid];
    float s = v.x * v.x + v.y * v.y + v.z * v.z + v.w * v.w;
#pragma unroll
    for (int m = 1; m < 64; m <<= 1) s += __shfl_xor(s, m, 64);
    __shared__ float wsum[4];
    if ((tid & 63) == 0) wsum[tid >> 6] = s;
    __syncthreads();
    float tot = wsum[0] + wsum[1] + wsum[2] + wsum[3];
    float scale = 1.0f / fmaxf(sqrtf(tot), 1e-12f);
    ushort4 o;
    o.x = f2bf(v.x * scale); o.y = f2bf(v.y * scale);
    o.z = f2bf(v.z * scale); o.w = f2bf(v.w * scale);
    ((ushort4*)(fnb + (size_t)row * K_D))[tid] = o;
    if (tid == 0) {
        rowsum[row] = 0.0f;                       // one row per block
        if (row == 0) { *possum = 0.0f; *counter = 0; }
    }
}

// 128x128 tile of sim = fn*fn^T. 4 waves in 2x2, each wave a 64x64 quadrant
// (4x4 frags of 16x16x32 bf16 MFMA). LDS layout XOR-swizzled: column-group cg
// of row r lives at slot (cg ^ (r&7)) -> fragment ds_read_b128 hits all 32
// banks with exactly 8 lanes each (zero conflicts). Staging permutes the
// GLOBAL source address instead (global_load_lds dest must stay lane-linear).
// Epilogue: e = exp(10*dot) off-diagonal; rowsum via 16-lane butterfly +
// atomics; possum via wave reduce + atomic. Last block finalizes the loss.
__global__ void gemm_exp_reduce(const unsigned short* __restrict__ fnb,
                                const int* __restrict__ labels,
                                float* __restrict__ rowsum,
                                float* __restrict__ possum,
                                int* __restrict__ counter,
                                float* __restrict__ out) {
    __shared__ __align__(16) unsigned short As[TILE * BK]; // 16 KB
    __shared__ __align__(16) unsigned short Bs[TILE * BK]; // 16 KB
    __shared__ int   rlab[TILE];
    __shared__ int   clab[TILE];
    __shared__ float fred[4];
    __shared__ int   isLast;

    const int bi = blockIdx.y, bj = blockIdx.x;
    const int row0 = bi * TILE, col0 = bj * TILE;
    const int tid  = threadIdx.x;
    const int lane = tid & 63, wave = tid >> 6;
    const int wr = wave >> 1, wc = wave & 1;
    const int quad = lane >> 4, l15 = lane & 15;

    if (tid < TILE) rlab[tid] = labels[row0 + tid];
    else            clab[tid - TILE] = labels[col0 + tid - TILE];

    f32x4 acc[4][4];
#pragma unroll
    for (int i = 0; i < 4; ++i)
#pragma unroll
        for (int j = 0; j < 4; ++j) {
            f32x4 z = {0.f, 0.f, 0.f, 0.f};
            acc[i][j] = z;
        }

    for (int k0 = 0; k0 < K_D; k0 += BK) {
        // chunk c covers LDS slot (r = c>>3, slot-group c&7); the data that
        // belongs there is global column-group (c&7) ^ (r&7) -- source swizzle.
#pragma unroll
        for (int it = 0; it < 4; ++it) {
            int c  = it * 256 + tid;
            int r  = c >> 3;
            int cg = ((c & 7) ^ (r & 7)) << 3;   // swizzled global col (elements)
            __builtin_amdgcn_global_load_lds(
                (const unsigned int*)(fnb + (size_t)(row0 + r) * K_D + k0 + cg),
                (unsigned int*)&As[c * 8], 16, 0, 0);
            __builtin_amdgcn_global_load_lds(
                (const unsigned int*)(fnb + (size_t)(col0 + r) * K_D + k0 + cg),
                (unsigned int*)&Bs[c * 8], 16, 0, 0);
        }
        __syncthreads();

#pragma unroll
        for (int ks = 0; ks < 2; ++ks) {   // kk = ks*32
            bf16x8 af[4], bf[4];
            const int gb = ks * 4 + quad;  // un-swizzled column group
#pragma unroll
            for (int fr = 0; fr < 4; ++fr)
                af[fr] = *(const bf16x8*)&As[(wr * 64 + fr * 16 + l15) * BK
                                             + ((gb ^ (l15 & 7)) << 3)];
#pragma unroll
            for (int fc = 0; fc < 4; ++fc)
                bf[fc] = *(const bf16x8*)&Bs[(wc * 64 + fc * 16 + l15) * BK
                                             + ((gb ^ (l15 & 7)) << 3)];
#pragma unroll
            for (int fr = 0; fr < 4; ++fr)
#pragma unroll
                for (int fc = 0; fc < 4; ++fc)
                    acc[fr][fc] = __builtin_amdgcn_mfma_f32_16x16x32_bf16(
                        af[fr], bf[fc], acc[fr][fc], 0, 0, 0);
        }
        __syncthreads();
    }

    // Epilogue. C/D layout (m89/m91-verified): col = lane&15, row = quad*4 + reg.
    // exp(10*x) = exp2(x * 10/ln2)
    const float ESC = 14.426950408889634f;
    float pospart = 0.0f;
#pragma unroll
    for (int fr = 0; fr < 4; ++fr) {
        float rp[4] = {0.f, 0.f, 0.f, 0.f};
#pragma unroll
        for (int fc = 0; fc < 4; ++fc) {
            int c    = wc * 64 + fc * 16 + l15;
            int gcol = col0 + c;
            int cl   = clab[c];
#pragma unroll
            for (int r = 0; r < 4; ++r) {
                int rr   = wr * 64 + fr * 16 + quad * 4 + r;
                int grow = row0 + rr;
                float e  = (grow == gcol) ? 0.0f : exp2f(acc[fr][fc][r] * ESC);
                rp[r] += e;
                pospart += (rlab[rr] == cl) ? e : 0.0f;
            }
        }
#pragma unroll
        for (int r = 0; r < 4; ++r) {
            float v = rp[r];
            v += __shfl_xor(v, 1, 64);
            v += __shfl_xor(v, 2, 64);
            v += __shfl_xor(v, 4, 64);
            v += __shfl_xor(v, 8, 64);
            if (l15 == 0)
                atomicAdd(&rowsum[row0 + wr * 64 + fr * 16 + quad * 4 + r], v);
        }
    }
#pragma unroll
    for (int m = 1; m < 64; m <<= 1) pospart += __shfl_xor(pospart, m, 64);
    if (lane == 0) atomicAdd(possum, pospart);

    // ---- last-block finalize (saves a dispatch) ----
    __threadfence();                              // release our atomics
    if (tid == 0) {
        int old = atomicAdd(counter, 1);
        isLast = (old == NBLK - 1);
    }
    __syncthreads();
    if (isLast) {
        // all other blocks' atomics are globally performed (their release
        // fence precedes their counter inc). Read via device-scope atomic
        // loads to stay coherent across XCD L2s.
        float s = 0.f;
        for (int i = tid; i < B_N; i += 256) {
            float rs = __hip_atomic_load(&rowsum[i], __ATOMIC_RELAXED,
                                         __HIP_MEMORY_SCOPE_AGENT);
            s += __logf(rs);
        }
#pragma unroll
        for (int m = 1; m < 64; m <<= 1) s += __shfl_xor(s, m, 64);
        if (lane == 0) fred[wave] = s;
        __syncthreads();
        if (tid == 0) {
            float tot = fred[0] + fred[1] + fred[2] + fred[3];
            float ps  = __hip_atomic_load(possum, __ATOMIC_RELAXED,
                                          __HIP_MEMORY_SCOPE_AGENT);
            out[0] = tot / (float)B_N - __logf(ps);
        }
    }
}

extern "C" void kernel_launch(void* const* d_in, const int* in_sizes, int n_in,
                              void* d_out, int out_size, void* d_ws, size_t ws_size,
                              hipStream_t stream) {
    const float* features = (const float*)d_in[0];
    const int*   targets  = (const int*)d_in[1];
    float*       out      = (float*)d_out;

    // ws: [bf16 fn: 8 MB][rowsum: 4096 f32][possum: 1 f32][counter: 1 int]
    unsigned short* fnb    = (unsigned short*)d_ws;
    float*          rowsum = (float*)((char*)d_ws + (size_t)B_N * K_D * sizeof(unsigned short));
    float*          possum = rowsum + B_N;
    int*            counter = (int*)(possum + 1);

    normalize_bf16<<<B_N, 256, 0, stream>>>(features, fnb, rowsum, possum, counter);
    dim3 grid(B_N / TILE, B_N / TILE);
    gemm_exp_reduce<<<grid, 256, 0, stream>>>(fnb, targets, rowsum, possum, counter, out);
}